// Round 18
// baseline (71.215 us; speedup 1.0000x reference)
//
#include <hip/hip_runtime.h>
#include <cstddef>
#include <cstdint>

#define SEQ 2048
#define DIM 1024
#define NH 16
#define HD 64
#define CK 64
#define NCK (SEQ / CK)     // 32 chunks
#define KVR 65             // KV^T rows incl. ksum row
#define KVRP 80            // padded to 5 MFMA tiles

typedef __attribute__((ext_vector_type(8))) short short8;            // 8 bf16
typedef __attribute__((ext_vector_type(8))) unsigned short ushort8;  // 8 raw bf16
typedef __attribute__((ext_vector_type(4))) float fx4;

__device__ __forceinline__ float phi_fn(float x) {
    return x > 0.f ? x + 1.f : __expf(x);   // elu(x)+1
}
__device__ __forceinline__ float bf2f(unsigned short u) {
    return __uint_as_float((unsigned int)u << 16);
}
__device__ __forceinline__ unsigned short f2bf(float f) {
    unsigned int u = __float_as_uint(f);
    unsigned int r = (u + 0x7FFFu + ((u >> 16) & 1u)) >> 16;   // RNE
    return (unsigned short)r;
}

// ---- GEMM swizzle (matched with global_load_lds pre-swizzled source) ----
__device__ __forceinline__ short8 lds_read_frag(const unsigned short* base, int row, int kcol) {
    int byte = row * 128 + kcol * 2; byte ^= (row & 7) << 4;
    return *(const short8*)((const char*)base + byte);
}

// ---- trio swizzle: byte ^= ((row&7)^((row>>3)&7))<<4 ----
__device__ __forceinline__ int swz_t(int row, int col) {
    int byte = row * 128 + col * 2;
    return byte ^ ((((row & 7) ^ ((row >> 3) & 7))) << 4);
}
__device__ __forceinline__ void lds_write16_t(unsigned short* base, int row, int col, ushort8 v) {
    *(ushort8*)((char*)base + swz_t(row, col)) = v;
}
__device__ __forceinline__ void lds_write2_t(unsigned short* base, int row, int col, unsigned short v) {
    *(unsigned short*)((char*)base + swz_t(row, col)) = v;
}
__device__ __forceinline__ short8 lds_read_frag_t(const unsigned short* base, int row, int kcol) {
    return *(const short8*)((const char*)base + swz_t(row, kcol));
}

template<int N> __device__ __forceinline__ void waitv() {
    if constexpr (N == 0)      asm volatile("s_waitcnt vmcnt(0)" ::: "memory");
    else if constexpr (N == 2) asm volatile("s_waitcnt vmcnt(2)" ::: "memory");
    else if constexpr (N == 3) asm volatile("s_waitcnt vmcnt(3)" ::: "memory");
    else if constexpr (N == 4) asm volatile("s_waitcnt vmcnt(4)" ::: "memory");
    else if constexpr (N == 6) asm volatile("s_waitcnt vmcnt(6)" ::: "memory");
    else if constexpr (N == 7) asm volatile("s_waitcnt vmcnt(7)" ::: "memory");
    else if constexpr (N == 8) asm volatile("s_waitcnt vmcnt(8)" ::: "memory");
    else                       asm volatile("s_waitcnt vmcnt(0)" ::: "memory");
}

// -------- fused prep: x->bf16, W_qkv^T->bf16, W_out^T->bf16 (one launch) --------
__global__ __launch_bounds__(256)
void prep_fused(const float* __restrict__ x, unsigned short* __restrict__ xb,
                const float* __restrict__ W1, unsigned short* __restrict__ WT1,
                const float* __restrict__ W2, unsigned short* __restrict__ WT2)
{
    __shared__ float t[32][33];
    int b = blockIdx.x;
    if (b < 2048) {                       // x -> bf16 : 2048*256*4 = 2M elements
        const int i = (b * 256 + threadIdx.x) * 4;
        float4 v = *(const float4*)&x[i];
        ushort4 o;
        o.x = f2bf(v.x); o.y = f2bf(v.y); o.z = f2bf(v.z); o.w = f2bf(v.w);
        *(ushort4*)&xb[i] = o;
        return;
    }
    b -= 2048;
    const float* W; unsigned short* WT; int N, kb, nb;
    if (b < 96 * 32) {
        W = W1; WT = WT1; N = 3 * DIM;
        nb = (b % 96) * 32; kb = (b / 96) * 32;
    } else {
        b -= 96 * 32;
        W = W2; WT = WT2; N = DIM;
        nb = (b % 32) * 32; kb = (b / 32) * 32;
    }
    const int c = threadIdx.x & 31, r0 = threadIdx.x >> 5;
    #pragma unroll
    for (int i = 0; i < 4; ++i) {
        const int r = r0 + i * 8;
        t[r][c] = W[(size_t)(kb + r) * N + nb + c];
    }
    __syncthreads();
    #pragma unroll
    for (int i = 0; i < 4; ++i) {
        const int r = r0 + i * 8;
        WT[(size_t)(nb + r) * DIM + kb + c] = f2bf(t[c][r]);
    }
}

// ====== pipelined bf16 MFMA GEMM, asymmetric A/B slot depths, BM=WAVES_M*64 ======
template<int WAVES_M, int WAVES_N, int NFRAG, int SLOTS_A, int SLOTS_B,
         int MINW, int OUT_BF16, int PHI>
__global__ __launch_bounds__(WAVES_M * WAVES_N * 64, MINW)
void gemm_pipe(const unsigned short* __restrict__ A,
               const unsigned short* __restrict__ BT,
               void* __restrict__ Cout, int M, int N, int K)
{
    constexpr int BM      = WAVES_M * 64;
    constexpr int BN      = WAVES_N * NFRAG * 16;
    constexpr int THREADS = WAVES_M * WAVES_N * 64;
    constexpr int CHUNK   = THREADS * 16;              // bytes per load-op
    constexpr int ALOADS  = (BM * 64 * 2) / CHUNK;
    constexpr int BLOADS  = (BN * 64 * 2) / CHUNK;
    constexpr int WAITN   = (SLOTS_A == 3 ? ALOADS : 0) + (SLOTS_B == 3 ? BLOADS : 0);

    __shared__ unsigned short As[SLOTS_A][BM * 64];
    __shared__ unsigned short Bs[SLOTS_B][BN * 64];

    const int tid = threadIdx.x, lane = tid & 63, wave = tid >> 6;
    const int wm = (wave / WAVES_N) * 64;
    const int wn = (wave % WAVES_N) * (NFRAG * 16);

    // XCD-aware block swizzle (nwg divisible by 8)
    int wg = blockIdx.y * gridDim.x + blockIdx.x;
    const int cpx = (gridDim.x * gridDim.y) >> 3;
    wg = (wg & 7) * cpx + (wg >> 3);
    const int bx = wg / gridDim.y;
    const int by = wg % gridDim.y;

    const int m0 = by * BM, n0 = bx * BN;
    const unsigned short* Abase = A + (size_t)m0 * K;
    const unsigned short* Bbase = BT + (size_t)n0 * K;
    const int nt = K >> 6;
    const int fr = lane & 15, fk = (lane >> 4) * 8;

    fx4 acc[4][NFRAG] = {};

    auto STAGE_A = [&](int slot, int t) {
        const int k0 = t << 6;
        #pragma unroll
        for (int q = 0; q < ALOADS; ++q) {
            const int L = q * CHUNK + tid * 16;                 // linear dest byte
            const int row = L >> 7;
            const int srcb = L ^ ((row & 7) << 4);              // inverse swizzle
            const unsigned short* g = Abase + (size_t)row * K + k0 + ((srcb & 127) >> 1);
            __builtin_amdgcn_global_load_lds(
                (const __attribute__((address_space(1))) void*)g,
                (__attribute__((address_space(3))) void*)((char*)&As[slot][0] + q * CHUNK + wave * 1024),
                16, 0, 0);
        }
    };
    auto STAGE_B = [&](int slot, int t) {
        const int k0 = t << 6;
        #pragma unroll
        for (int q = 0; q < BLOADS; ++q) {
            const int L = q * CHUNK + tid * 16;
            const int row = L >> 7;
            const int srcb = L ^ ((row & 7) << 4);
            const unsigned short* g = Bbase + (size_t)row * K + k0 + ((srcb & 127) >> 1);
            __builtin_amdgcn_global_load_lds(
                (const __attribute__((address_space(1))) void*)g,
                (__attribute__((address_space(3))) void*)((char*)&Bs[slot][0] + q * CHUNK + wave * 1024),
                16, 0, 0);
        }
    };

    // prologue: fill first tiles; keep only distance-2 tiles in flight
    STAGE_A(0, 0); STAGE_B(0, 0);
    if constexpr (SLOTS_A == 3) STAGE_A(1, 1);
    if constexpr (SLOTS_B == 3) STAGE_B(1, 1);
    waitv<WAITN>();
    __builtin_amdgcn_s_barrier();

    int ca = 0, cb = 0;
    for (int t = 0; t < nt; ++t) {
        short8 a0[4], a1[4], b0[NFRAG], b1[NFRAG];
        #pragma unroll
        for (int i = 0; i < 4; ++i) {
            a0[i] = lds_read_frag(&As[ca][0], wm + i * 16 + fr, fk);
            a1[i] = lds_read_frag(&As[ca][0], wm + i * 16 + fr, 32 + fk);
        }
        #pragma unroll
        for (int j = 0; j < NFRAG; ++j) {
            b0[j] = lds_read_frag(&Bs[cb][0], wn + j * 16 + fr, fk);
            b1[j] = lds_read_frag(&Bs[cb][0], wn + j * 16 + fr, 32 + fk);
        }

        // stage future tiles into freed slots (readers drained last iteration)
        if (t + SLOTS_A - 1 < nt)
            STAGE_A((ca + SLOTS_A - 1) % SLOTS_A, t + SLOTS_A - 1);
        if (t + SLOTS_B - 1 < nt)
            STAGE_B((cb + SLOTS_B - 1) % SLOTS_B, t + SLOTS_B - 1);

        __builtin_amdgcn_s_setprio(1);
        #pragma unroll
        for (int i = 0; i < 4; ++i)
            #pragma unroll
            for (int j = 0; j < NFRAG; ++j)
                acc[i][j] = __builtin_amdgcn_mfma_f32_16x16x32_bf16(a0[i], b0[j], acc[i][j], 0, 0, 0);
        #pragma unroll
        for (int i = 0; i < 4; ++i)
            #pragma unroll
            for (int j = 0; j < NFRAG; ++j)
                acc[i][j] = __builtin_amdgcn_mfma_f32_16x16x32_bf16(a1[i], b1[j], acc[i][j], 0, 0, 0);
        __builtin_amdgcn_s_setprio(0);

        // SLOTS=3 sides keep their distance-2 tile in flight; SLOTS=2 drains
        if (t + 2 < nt) waitv<WAITN>(); else waitv<0>();
        __builtin_amdgcn_s_barrier();
        ca = (ca + 1) % SLOTS_A;
        cb = (cb + 1) % SLOTS_B;
    }

    // C/D layout: col = lane&15, row = (lane>>4)*4 + reg
    const int cr = (lane >> 4) * 4, cc = lane & 15;
    #pragma unroll
    for (int i = 0; i < 4; ++i)
        #pragma unroll
        for (int j = 0; j < NFRAG; ++j) {
            const int m = m0 + wm + i * 16 + cr;
            const int n = n0 + wn + j * 16 + cc;
            #pragma unroll
            for (int r = 0; r < 4; ++r) {
                float v = acc[i][j][r];
                if (PHI && n < 2 * DIM) v = phi_fn(v);   // q,k -> phi(q),phi(k)
                if (OUT_BF16)
                    ((unsigned short*)Cout)[(size_t)(m + r) * N + n] = f2bf(v);
                else
                    ((float*)Cout)[(size_t)(m + r) * N + n] = v;
            }
        }
}

// ---------------- Phase A: per-(head,chunk) KV^T sums via MFMA (bf16 out) ----
__global__ __launch_bounds__(256)
void chunk_kv(const unsigned short* __restrict__ qkv, unsigned short* __restrict__ kvs)
{
    const int c = blockIdx.x, h = blockIdx.y;
    __shared__ unsigned short kT[64 * 64];    // [i=d][s], trio-swizzled
    __shared__ unsigned short vT[KVRP * 64];  // [j][s], row64=ones, 65-79=0
    const int tid = threadIdx.x, lane = tid & 63, wave = tid >> 6;
    const int s0 = c * CK;

    #pragma unroll
    for (int part = 0; part < 2; ++part) {
        const int s = (tid >> 3) + part * 32;
        const int d0 = (tid & 7) * 8;
        const size_t base = (size_t)(s0 + s) * (3 * DIM) + (size_t)h * HD + d0;
        ushort8 kk = *(const ushort8*)&qkv[base + DIM];
        ushort8 vv = *(const ushort8*)&qkv[base + 2 * DIM];
        #pragma unroll
        for (int u = 0; u < 8; ++u) {
            lds_write2_t(kT, d0 + u, s, kk[u]);
            lds_write2_t(vT, d0 + u, s, vv[u]);
        }
    }
    if (tid < 64) lds_write2_t(vT, 64, tid, 0x3F80);   // bf16 1.0
    for (int idx = tid; idx < 15 * 64; idx += 256)
        lds_write2_t(vT, 65 + (idx >> 6), idx & 63, 0);
    __syncthreads();

    fx4 acc[5] = {};
    #pragma unroll
    for (int ks = 0; ks < 2; ++ks) {
        short8 b = lds_read_frag_t(kT, wave * 16 + (lane & 15), ks * 32 + (lane >> 4) * 8);
        #pragma unroll
        for (int mt = 0; mt < 5; ++mt) {
            short8 a = lds_read_frag_t(vT, mt * 16 + (lane & 15), ks * 32 + (lane >> 4) * 8);
            acc[mt] = __builtin_amdgcn_mfma_f32_16x16x32_bf16(a, b, acc[mt], 0, 0, 0);
        }
    }
    unsigned short* dst = kvs + (size_t)(h * NCK + c) * KVR * 64;
    const int i = wave * 16 + (lane & 15);
    #pragma unroll
    for (int mt = 0; mt < 5; ++mt)
        #pragma unroll
        for (int t = 0; t < 4; ++t) {
            const int j = mt * 16 + (lane >> 4) * 4 + t;
            if (j < KVR) dst[(size_t)j * 64 + i] = f2bf(acc[mt][t]);
        }
}

// ---------------- Phase C: per-(head,chunk) outputs via MFMA ----------------
// Prefix sum of chunk KV^T built IN-KERNEL: chunk_kv completed (stream order),
// so each block sums chunks 0..c-1 of kvs directly during kvp staging —
// removes the scan_kv launch + gap; per-head kvs (266 KB) is L2-resident.
__global__ __launch_bounds__(256)
void attn_chunk(const unsigned short* __restrict__ qkv,
                const unsigned short* __restrict__ kvs,
                unsigned short* __restrict__ attnb)
{
    const int c = blockIdx.x, h = blockIdx.y;
    __shared__ unsigned short q_s[64 * 64];   // phi_q [r][d]
    __shared__ unsigned short k_s[64 * 64];   // phi_k [s][d]
    __shared__ unsigned short p_s[64 * 64];   // masked P bf16 [r][s]
    __shared__ unsigned short vT[KVRP * 64];  // V^T [j][s], row64=ones
    __shared__ unsigned short kvp[KVRP * 64]; // KVp^T_aug [j][d], row64=ksp
    const int tid = threadIdx.x, lane = tid & 63, wave = tid >> 6;
    const int s0 = c * CK;

    #pragma unroll
    for (int part = 0; part < 2; ++part) {
        const int s = (tid >> 3) + part * 32;
        const int d0 = (tid & 7) * 8;
        const size_t base = (size_t)(s0 + s) * (3 * DIM) + (size_t)h * HD + d0;
        ushort8 qq = *(const ushort8*)&qkv[base];
        ushort8 kk = *(const ushort8*)&qkv[base + DIM];
        ushort8 vv = *(const ushort8*)&qkv[base + 2 * DIM];
        lds_write16_t(q_s, s, d0, qq);
        lds_write16_t(k_s, s, d0, kk);
        #pragma unroll
        for (int u = 0; u < 8; ++u)
            lds_write2_t(vT, d0 + u, s, vv[u]);
    }
    {
        // exclusive prefix over chunks 0..c-1 (f32 accumulate, single bf16 round)
        const unsigned short* kv_base = kvs + (size_t)h * NCK * KVR * 64;
        for (int idx = tid * 8; idx < KVR * 64; idx += 2048) {
            float s8[8] = {};
            for (int c2 = 0; c2 < c; ++c2) {
                ushort8 v8 = *(const ushort8*)&kv_base[(size_t)c2 * KVR * 64 + idx];
                #pragma unroll
                for (int u = 0; u < 8; ++u) s8[u] += bf2f(v8[u]);
            }
            ushort8 o;
            #pragma unroll
            for (int u = 0; u < 8; ++u) o[u] = f2bf(s8[u]);
            lds_write16_t(kvp, idx >> 6, idx & 63, o);
        }
    }
    if (tid < 64) lds_write2_t(vT, 64, tid, 0x3F80);
    for (int idx = tid; idx < 15 * 64; idx += 256) {
        lds_write2_t(vT, 65 + (idx >> 6), idx & 63, 0);
        lds_write2_t(kvp, 65 + (idx >> 6), idx & 63, 0);
    }
    __syncthreads();

    const int r0 = wave * 16;
    fx4 accp[4] = {};
    #pragma unroll
    for (int ks = 0; ks < 2; ++ks) {
        short8 aq = lds_read_frag_t(q_s, r0 + (lane & 15), ks * 32 + (lane >> 4) * 8);
        #pragma unroll
        for (int nt = 0; nt < 4; ++nt) {
            short8 bk = lds_read_frag_t(k_s, nt * 16 + (lane & 15), ks * 32 + (lane >> 4) * 8);
            accp[nt] = __builtin_amdgcn_mfma_f32_16x16x32_bf16(aq, bk, accp[nt], 0, 0, 0);
        }
    }
    #pragma unroll
    for (int nt = 0; nt < 4; ++nt)
        #pragma unroll
        for (int t = 0; t < 4; ++t) {
            const int r = r0 + (lane >> 4) * 4 + t, sc = nt * 16 + (lane & 15);
            lds_write2_t(p_s, r, sc, (sc <= r) ? f2bf(accp[nt][t]) : (unsigned short)0);
        }
    __syncthreads();

    fx4 acc[5] = {};
    #pragma unroll
    for (int ks = 0; ks < 2; ++ks) {
        short8 ap = lds_read_frag_t(p_s, r0 + (lane & 15), ks * 32 + (lane >> 4) * 8);
        short8 aq = lds_read_frag_t(q_s, r0 + (lane & 15), ks * 32 + (lane >> 4) * 8);
        #pragma unroll
        for (int nt = 0; nt < 5; ++nt) {
            short8 bv  = lds_read_frag_t(vT,  nt * 16 + (lane & 15), ks * 32 + (lane >> 4) * 8);
            short8 bkv = lds_read_frag_t(kvp, nt * 16 + (lane & 15), ks * 32 + (lane >> 4) * 8);
            acc[nt] = __builtin_amdgcn_mfma_f32_16x16x32_bf16(ap, bv,  acc[nt], 0, 0, 0);
            acc[nt] = __builtin_amdgcn_mfma_f32_16x16x32_bf16(aq, bkv, acc[nt], 0, 0, 0);
        }
    }
    float dinv[4];
    #pragma unroll
    for (int t = 0; t < 4; ++t) {
        const float d = __shfl(acc[4][t], lane & 48, 64);
        dinv[t] = 1.f / (d + 1e-6f);
    }
    #pragma unroll
    for (int nt = 0; nt < 4; ++nt)
        #pragma unroll
        for (int t = 0; t < 4; ++t) {
            const int r = r0 + (lane >> 4) * 4 + t, j = nt * 16 + (lane & 15);
            attnb[(size_t)(s0 + r) * DIM + (size_t)h * HD + j] = f2bf(acc[nt][t] * dinv[t]);
        }
}

extern "C" void kernel_launch(void* const* d_in, const int* in_sizes, int n_in,
                              void* d_out, int out_size, void* d_ws, size_t ws_size,
                              hipStream_t stream)
{
    const float* x     = (const float*)d_in[0];
    const float* W_qkv = (const float*)d_in[2];
    const float* W_out = (const float*)d_in[3];
    float* out = (float*)d_out;

    char* ws = (char*)d_ws;
    size_t off = 0;
    unsigned short* qkvb = (unsigned short*)(ws + off); off += (size_t)SEQ * 3 * DIM * 2;       // 12.6 MB
    unsigned short* xb   = (unsigned short*)(ws + off); off += (size_t)SEQ * DIM * 2;           //  4.2 MB
    unsigned short* kvs  = (unsigned short*)(ws + off); off += (size_t)NH * NCK * KVR * 64 * 2; //  4.3 MB
    unsigned short* wqt  = (unsigned short*)(ws + off); off += (size_t)3 * DIM * DIM * 2;       //  6.3 MB
    unsigned short* wot  = (unsigned short*)(ws + off); off += (size_t)DIM * DIM * 2;           //  2.1 MB
    unsigned short* attnb = xb;   // alias: qkv-GEMM finishes reading xb first (stream order)

    dim3 blk(256);

    prep_fused<<<dim3(2048 + 96 * 32 + 32 * 32), blk, 0, stream>>>(
        x, xb, W_qkv, wqt, W_out, wot);

    // qkv = x @ W_qkv (phi fused): R16-best — BM=128, BN=96, 4 waves (2x2,
    // per-wave 64x48), A 2-slot + B 3-slot = 68KB LDS -> 2 blocks/CU;
    // grid 32x16 = 512 = 2/CU.
    gemm_pipe<2, 2, 3, 2, 3, 2, 1, 1><<<dim3(3 * DIM / 96, SEQ / 128), dim3(256), 0, stream>>>(
        xb, wqt, qkvb, SEQ, 3 * DIM, DIM);

    chunk_kv<<<dim3(NCK, NH), blk, 0, stream>>>(qkvb, kvs);
    attn_chunk<<<dim3(NCK, NH), blk, 0, stream>>>(qkvb, kvs, attnb);

    // out = attn @ W_out : BM=64 (WAVES_M=1, 4 waves 1x4, per-wave 64x16),
    // BN=64, 3-slot/3-slot = 48KB LDS -> grid 16x32 = 512 = 2 blocks/CU.
    gemm_pipe<1, 4, 1, 3, 3, 2, 0, 0><<<dim3(DIM / 64, SEQ / 64), dim3(256), 0, stream>>>(
        attnb, wot, out, SEQ, DIM, DIM);
}

// Round 19
// 55.505 us; speedup vs baseline: 1.2830x; 1.2830x over previous
//
#include <hip/hip_runtime.h>
#include <cstddef>
#include <cstdint>

#define SEQ 2048
#define DIM 1024
#define NH 16
#define HD 64
#define CK 64
#define NCK (SEQ / CK)     // 32 chunks
#define KVR 65             // KV^T rows incl. ksum row
#define KVRP 80            // padded to 5 MFMA tiles

typedef __attribute__((ext_vector_type(8))) short short8;            // 8 bf16
typedef __attribute__((ext_vector_type(8))) unsigned short ushort8;  // 8 raw bf16
typedef __attribute__((ext_vector_type(4))) float fx4;

__device__ __forceinline__ float phi_fn(float x) {
    return x > 0.f ? x + 1.f : __expf(x);   // elu(x)+1
}
__device__ __forceinline__ float bf2f(unsigned short u) {
    return __uint_as_float((unsigned int)u << 16);
}
__device__ __forceinline__ unsigned short f2bf(float f) {
    unsigned int u = __float_as_uint(f);
    unsigned int r = (u + 0x7FFFu + ((u >> 16) & 1u)) >> 16;   // RNE
    return (unsigned short)r;
}

// ---- GEMM swizzle (matched with global_load_lds pre-swizzled source) ----
__device__ __forceinline__ short8 lds_read_frag(const unsigned short* base, int row, int kcol) {
    int byte = row * 128 + kcol * 2; byte ^= (row & 7) << 4;
    return *(const short8*)((const char*)base + byte);
}

// ---- trio swizzle: byte ^= ((row&7)^((row>>3)&7))<<4 ----
__device__ __forceinline__ int swz_t(int row, int col) {
    int byte = row * 128 + col * 2;
    return byte ^ ((((row & 7) ^ ((row >> 3) & 7))) << 4);
}
__device__ __forceinline__ void lds_write16_t(unsigned short* base, int row, int col, ushort8 v) {
    *(ushort8*)((char*)base + swz_t(row, col)) = v;
}
__device__ __forceinline__ void lds_write2_t(unsigned short* base, int row, int col, unsigned short v) {
    *(unsigned short*)((char*)base + swz_t(row, col)) = v;
}
__device__ __forceinline__ short8 lds_read_frag_t(const unsigned short* base, int row, int kcol) {
    return *(const short8*)((const char*)base + swz_t(row, kcol));
}

template<int N> __device__ __forceinline__ void waitv() {
    if constexpr (N == 0)      asm volatile("s_waitcnt vmcnt(0)" ::: "memory");
    else if constexpr (N == 2) asm volatile("s_waitcnt vmcnt(2)" ::: "memory");
    else if constexpr (N == 3) asm volatile("s_waitcnt vmcnt(3)" ::: "memory");
    else if constexpr (N == 4) asm volatile("s_waitcnt vmcnt(4)" ::: "memory");
    else if constexpr (N == 6) asm volatile("s_waitcnt vmcnt(6)" ::: "memory");
    else if constexpr (N == 7) asm volatile("s_waitcnt vmcnt(7)" ::: "memory");
    else if constexpr (N == 8) asm volatile("s_waitcnt vmcnt(8)" ::: "memory");
    else                       asm volatile("s_waitcnt vmcnt(0)" ::: "memory");
}

// -------- fused prep: x->bf16, W_qkv^T->bf16, W_out^T->bf16 (one launch) --------
__global__ __launch_bounds__(256)
void prep_fused(const float* __restrict__ x, unsigned short* __restrict__ xb,
                const float* __restrict__ W1, unsigned short* __restrict__ WT1,
                const float* __restrict__ W2, unsigned short* __restrict__ WT2)
{
    __shared__ float t[32][33];
    int b = blockIdx.x;
    if (b < 2048) {                       // x -> bf16 : 2048*256*4 = 2M elements
        const int i = (b * 256 + threadIdx.x) * 4;
        float4 v = *(const float4*)&x[i];
        ushort4 o;
        o.x = f2bf(v.x); o.y = f2bf(v.y); o.z = f2bf(v.z); o.w = f2bf(v.w);
        *(ushort4*)&xb[i] = o;
        return;
    }
    b -= 2048;
    const float* W; unsigned short* WT; int N, kb, nb;
    if (b < 96 * 32) {
        W = W1; WT = WT1; N = 3 * DIM;
        nb = (b % 96) * 32; kb = (b / 96) * 32;
    } else {
        b -= 96 * 32;
        W = W2; WT = WT2; N = DIM;
        nb = (b % 32) * 32; kb = (b / 32) * 32;
    }
    const int c = threadIdx.x & 31, r0 = threadIdx.x >> 5;
    #pragma unroll
    for (int i = 0; i < 4; ++i) {
        const int r = r0 + i * 8;
        t[r][c] = W[(size_t)(kb + r) * N + nb + c];
    }
    __syncthreads();
    #pragma unroll
    for (int i = 0; i < 4; ++i) {
        const int r = r0 + i * 8;
        WT[(size_t)(nb + r) * DIM + kb + c] = f2bf(t[c][r]);
    }
}

// ====== pipelined bf16 MFMA GEMM, asymmetric A/B slot depths, BM=WAVES_M*64 ======
template<int WAVES_M, int WAVES_N, int NFRAG, int SLOTS_A, int SLOTS_B,
         int MINW, int OUT_BF16, int PHI>
__global__ __launch_bounds__(WAVES_M * WAVES_N * 64, MINW)
void gemm_pipe(const unsigned short* __restrict__ A,
               const unsigned short* __restrict__ BT,
               void* __restrict__ Cout, int M, int N, int K)
{
    constexpr int BM      = WAVES_M * 64;
    constexpr int BN      = WAVES_N * NFRAG * 16;
    constexpr int THREADS = WAVES_M * WAVES_N * 64;
    constexpr int CHUNK   = THREADS * 16;              // bytes per load-op
    constexpr int ALOADS  = (BM * 64 * 2) / CHUNK;
    constexpr int BLOADS  = (BN * 64 * 2) / CHUNK;
    constexpr int WAITN   = (SLOTS_A == 3 ? ALOADS : 0) + (SLOTS_B == 3 ? BLOADS : 0);

    __shared__ unsigned short As[SLOTS_A][BM * 64];
    __shared__ unsigned short Bs[SLOTS_B][BN * 64];

    const int tid = threadIdx.x, lane = tid & 63, wave = tid >> 6;
    const int wm = (wave / WAVES_N) * 64;
    const int wn = (wave % WAVES_N) * (NFRAG * 16);

    // XCD-aware block swizzle (nwg divisible by 8)
    int wg = blockIdx.y * gridDim.x + blockIdx.x;
    const int cpx = (gridDim.x * gridDim.y) >> 3;
    wg = (wg & 7) * cpx + (wg >> 3);
    const int bx = wg / gridDim.y;
    const int by = wg % gridDim.y;

    const int m0 = by * BM, n0 = bx * BN;
    const unsigned short* Abase = A + (size_t)m0 * K;
    const unsigned short* Bbase = BT + (size_t)n0 * K;
    const int nt = K >> 6;
    const int fr = lane & 15, fk = (lane >> 4) * 8;

    fx4 acc[4][NFRAG] = {};

    auto STAGE_A = [&](int slot, int t) {
        const int k0 = t << 6;
        #pragma unroll
        for (int q = 0; q < ALOADS; ++q) {
            const int L = q * CHUNK + tid * 16;                 // linear dest byte
            const int row = L >> 7;
            const int srcb = L ^ ((row & 7) << 4);              // inverse swizzle
            const unsigned short* g = Abase + (size_t)row * K + k0 + ((srcb & 127) >> 1);
            __builtin_amdgcn_global_load_lds(
                (const __attribute__((address_space(1))) void*)g,
                (__attribute__((address_space(3))) void*)((char*)&As[slot][0] + q * CHUNK + wave * 1024),
                16, 0, 0);
        }
    };
    auto STAGE_B = [&](int slot, int t) {
        const int k0 = t << 6;
        #pragma unroll
        for (int q = 0; q < BLOADS; ++q) {
            const int L = q * CHUNK + tid * 16;
            const int row = L >> 7;
            const int srcb = L ^ ((row & 7) << 4);
            const unsigned short* g = Bbase + (size_t)row * K + k0 + ((srcb & 127) >> 1);
            __builtin_amdgcn_global_load_lds(
                (const __attribute__((address_space(1))) void*)g,
                (__attribute__((address_space(3))) void*)((char*)&Bs[slot][0] + q * CHUNK + wave * 1024),
                16, 0, 0);
        }
    };

    // prologue: fill first tiles; keep only distance-2 tiles in flight
    STAGE_A(0, 0); STAGE_B(0, 0);
    if constexpr (SLOTS_A == 3) STAGE_A(1, 1);
    if constexpr (SLOTS_B == 3) STAGE_B(1, 1);
    waitv<WAITN>();
    __builtin_amdgcn_s_barrier();

    int ca = 0, cb = 0;
    for (int t = 0; t < nt; ++t) {
        short8 a0[4], a1[4], b0[NFRAG], b1[NFRAG];
        #pragma unroll
        for (int i = 0; i < 4; ++i) {
            a0[i] = lds_read_frag(&As[ca][0], wm + i * 16 + fr, fk);
            a1[i] = lds_read_frag(&As[ca][0], wm + i * 16 + fr, 32 + fk);
        }
        #pragma unroll
        for (int j = 0; j < NFRAG; ++j) {
            b0[j] = lds_read_frag(&Bs[cb][0], wn + j * 16 + fr, fk);
            b1[j] = lds_read_frag(&Bs[cb][0], wn + j * 16 + fr, 32 + fk);
        }

        // stage future tiles into freed slots (readers drained last iteration)
        if (t + SLOTS_A - 1 < nt)
            STAGE_A((ca + SLOTS_A - 1) % SLOTS_A, t + SLOTS_A - 1);
        if (t + SLOTS_B - 1 < nt)
            STAGE_B((cb + SLOTS_B - 1) % SLOTS_B, t + SLOTS_B - 1);

        __builtin_amdgcn_s_setprio(1);
        #pragma unroll
        for (int i = 0; i < 4; ++i)
            #pragma unroll
            for (int j = 0; j < NFRAG; ++j)
                acc[i][j] = __builtin_amdgcn_mfma_f32_16x16x32_bf16(a0[i], b0[j], acc[i][j], 0, 0, 0);
        #pragma unroll
        for (int i = 0; i < 4; ++i)
            #pragma unroll
            for (int j = 0; j < NFRAG; ++j)
                acc[i][j] = __builtin_amdgcn_mfma_f32_16x16x32_bf16(a1[i], b1[j], acc[i][j], 0, 0, 0);
        __builtin_amdgcn_s_setprio(0);

        // SLOTS=3 sides keep their distance-2 tile in flight; SLOTS=2 drains
        if (t + 2 < nt) waitv<WAITN>(); else waitv<0>();
        __builtin_amdgcn_s_barrier();
        ca = (ca + 1) % SLOTS_A;
        cb = (cb + 1) % SLOTS_B;
    }

    // C/D layout: col = lane&15, row = (lane>>4)*4 + reg
    const int cr = (lane >> 4) * 4, cc = lane & 15;
    #pragma unroll
    for (int i = 0; i < 4; ++i)
        #pragma unroll
        for (int j = 0; j < NFRAG; ++j) {
            const int m = m0 + wm + i * 16 + cr;
            const int n = n0 + wn + j * 16 + cc;
            #pragma unroll
            for (int r = 0; r < 4; ++r) {
                float v = acc[i][j][r];
                if (PHI && n < 2 * DIM) v = phi_fn(v);   // q,k -> phi(q),phi(k)
                if (OUT_BF16)
                    ((unsigned short*)Cout)[(size_t)(m + r) * N + n] = f2bf(v);
                else
                    ((float*)Cout)[(size_t)(m + r) * N + n] = v;
            }
        }
}

// ---------------- Phase A: per-(head,chunk) KV^T sums via MFMA (bf16 out) ----
__global__ __launch_bounds__(256)
void chunk_kv(const unsigned short* __restrict__ qkv, unsigned short* __restrict__ kvs)
{
    const int c = blockIdx.x, h = blockIdx.y;
    __shared__ unsigned short kT[64 * 64];    // [i=d][s], trio-swizzled
    __shared__ unsigned short vT[KVRP * 64];  // [j][s], row64=ones, 65-79=0
    const int tid = threadIdx.x, lane = tid & 63, wave = tid >> 6;
    const int s0 = c * CK;

    #pragma unroll
    for (int part = 0; part < 2; ++part) {
        const int s = (tid >> 3) + part * 32;
        const int d0 = (tid & 7) * 8;
        const size_t base = (size_t)(s0 + s) * (3 * DIM) + (size_t)h * HD + d0;
        ushort8 kk = *(const ushort8*)&qkv[base + DIM];
        ushort8 vv = *(const ushort8*)&qkv[base + 2 * DIM];
        #pragma unroll
        for (int u = 0; u < 8; ++u) {
            lds_write2_t(kT, d0 + u, s, kk[u]);
            lds_write2_t(vT, d0 + u, s, vv[u]);
        }
    }
    if (tid < 64) lds_write2_t(vT, 64, tid, 0x3F80);   // bf16 1.0
    for (int idx = tid; idx < 15 * 64; idx += 256)
        lds_write2_t(vT, 65 + (idx >> 6), idx & 63, 0);
    __syncthreads();

    fx4 acc[5] = {};
    #pragma unroll
    for (int ks = 0; ks < 2; ++ks) {
        short8 b = lds_read_frag_t(kT, wave * 16 + (lane & 15), ks * 32 + (lane >> 4) * 8);
        #pragma unroll
        for (int mt = 0; mt < 5; ++mt) {
            short8 a = lds_read_frag_t(vT, mt * 16 + (lane & 15), ks * 32 + (lane >> 4) * 8);
            acc[mt] = __builtin_amdgcn_mfma_f32_16x16x32_bf16(a, b, acc[mt], 0, 0, 0);
        }
    }
    unsigned short* dst = kvs + (size_t)(h * NCK + c) * KVR * 64;
    const int i = wave * 16 + (lane & 15);
    #pragma unroll
    for (int mt = 0; mt < 5; ++mt)
        #pragma unroll
        for (int t = 0; t < 4; ++t) {
            const int j = mt * 16 + (lane >> 4) * 4 + t;
            if (j < KVR) dst[(size_t)j * 64 + i] = f2bf(acc[mt][t]);
        }
}

// ---------------- Phase B: exclusive prefix scan (ILP loads), bf16 in/out ----
__global__ __launch_bounds__(256)
void scan_kv(const unsigned short* __restrict__ kvs, unsigned short* __restrict__ kvpb)
{
    const int e = blockIdx.x * 256 + threadIdx.x;
    if (e >= NH * KVR * 64) return;
    const int h = e / (KVR * 64), off = e % (KVR * 64);
    const unsigned short* src = kvs + (size_t)h * NCK * KVR * 64 + off;
    unsigned short* dst = kvpb + (size_t)h * NCK * KVR * 64 + off;
    float v[NCK];
    #pragma unroll
    for (int c2 = 0; c2 < NCK; ++c2) v[c2] = bf2f(src[(size_t)c2 * KVR * 64]);
    float run = 0.f;
    #pragma unroll
    for (int c2 = 0; c2 < NCK; ++c2) {
        dst[(size_t)c2 * KVR * 64] = f2bf(run);
        run += v[c2];
    }
}

// ---------------- Phase C: per-(head,chunk) outputs via MFMA ----------------
__global__ __launch_bounds__(256)
void attn_chunk(const unsigned short* __restrict__ qkv,
                const unsigned short* __restrict__ kvpb,
                unsigned short* __restrict__ attnb)
{
    const int c = blockIdx.x, h = blockIdx.y;
    __shared__ unsigned short q_s[64 * 64];   // phi_q [r][d]
    __shared__ unsigned short k_s[64 * 64];   // phi_k [s][d]
    __shared__ unsigned short p_s[64 * 64];   // masked P bf16 [r][s]
    __shared__ unsigned short vT[KVRP * 64];  // V^T [j][s], row64=ones
    __shared__ unsigned short kvp[KVRP * 64]; // KVp^T_aug [j][d], row64=ksp
    const int tid = threadIdx.x, lane = tid & 63, wave = tid >> 6;
    const int s0 = c * CK;

    #pragma unroll
    for (int part = 0; part < 2; ++part) {
        const int s = (tid >> 3) + part * 32;
        const int d0 = (tid & 7) * 8;
        const size_t base = (size_t)(s0 + s) * (3 * DIM) + (size_t)h * HD + d0;
        ushort8 qq = *(const ushort8*)&qkv[base];
        ushort8 kk = *(const ushort8*)&qkv[base + DIM];
        ushort8 vv = *(const ushort8*)&qkv[base + 2 * DIM];
        lds_write16_t(q_s, s, d0, qq);
        lds_write16_t(k_s, s, d0, kk);
        #pragma unroll
        for (int u = 0; u < 8; ++u)
            lds_write2_t(vT, d0 + u, s, vv[u]);
    }
    {
        const unsigned short* kv_src = kvpb + (size_t)(h * NCK + c) * KVR * 64;
        for (int idx = tid * 8; idx < KVR * 64; idx += 2048) {
            ushort8 kv8 = *(const ushort8*)&kv_src[idx];
            lds_write16_t(kvp, idx >> 6, idx & 63, kv8);
        }
    }
    if (tid < 64) lds_write2_t(vT, 64, tid, 0x3F80);
    for (int idx = tid; idx < 15 * 64; idx += 256) {
        lds_write2_t(vT, 65 + (idx >> 6), idx & 63, 0);
        lds_write2_t(kvp, 65 + (idx >> 6), idx & 63, 0);
    }
    __syncthreads();

    const int r0 = wave * 16;
    fx4 accp[4] = {};
    #pragma unroll
    for (int ks = 0; ks < 2; ++ks) {
        short8 aq = lds_read_frag_t(q_s, r0 + (lane & 15), ks * 32 + (lane >> 4) * 8);
        #pragma unroll
        for (int nt = 0; nt < 4; ++nt) {
            short8 bk = lds_read_frag_t(k_s, nt * 16 + (lane & 15), ks * 32 + (lane >> 4) * 8);
            accp[nt] = __builtin_amdgcn_mfma_f32_16x16x32_bf16(aq, bk, accp[nt], 0, 0, 0);
        }
    }
    #pragma unroll
    for (int nt = 0; nt < 4; ++nt)
        #pragma unroll
        for (int t = 0; t < 4; ++t) {
            const int r = r0 + (lane >> 4) * 4 + t, sc = nt * 16 + (lane & 15);
            lds_write2_t(p_s, r, sc, (sc <= r) ? f2bf(accp[nt][t]) : (unsigned short)0);
        }
    __syncthreads();

    fx4 acc[5] = {};
    #pragma unroll
    for (int ks = 0; ks < 2; ++ks) {
        short8 ap = lds_read_frag_t(p_s, r0 + (lane & 15), ks * 32 + (lane >> 4) * 8);
        short8 aq = lds_read_frag_t(q_s, r0 + (lane & 15), ks * 32 + (lane >> 4) * 8);
        #pragma unroll
        for (int nt = 0; nt < 5; ++nt) {
            short8 bv  = lds_read_frag_t(vT,  nt * 16 + (lane & 15), ks * 32 + (lane >> 4) * 8);
            short8 bkv = lds_read_frag_t(kvp, nt * 16 + (lane & 15), ks * 32 + (lane >> 4) * 8);
            acc[nt] = __builtin_amdgcn_mfma_f32_16x16x32_bf16(ap, bv,  acc[nt], 0, 0, 0);
            acc[nt] = __builtin_amdgcn_mfma_f32_16x16x32_bf16(aq, bkv, acc[nt], 0, 0, 0);
        }
    }
    float dinv[4];
    #pragma unroll
    for (int t = 0; t < 4; ++t) {
        const float d = __shfl(acc[4][t], lane & 48, 64);
        dinv[t] = 1.f / (d + 1e-6f);
    }
    #pragma unroll
    for (int nt = 0; nt < 4; ++nt)
        #pragma unroll
        for (int t = 0; t < 4; ++t) {
            const int r = r0 + (lane >> 4) * 4 + t, j = nt * 16 + (lane & 15);
            attnb[(size_t)(s0 + r) * DIM + (size_t)h * HD + j] = f2bf(acc[nt][t] * dinv[t]);
        }
}

extern "C" void kernel_launch(void* const* d_in, const int* in_sizes, int n_in,
                              void* d_out, int out_size, void* d_ws, size_t ws_size,
                              hipStream_t stream)
{
    const float* x     = (const float*)d_in[0];
    const float* W_qkv = (const float*)d_in[2];
    const float* W_out = (const float*)d_in[3];
    float* out = (float*)d_out;

    char* ws = (char*)d_ws;
    size_t off = 0;
    unsigned short* qkvb = (unsigned short*)(ws + off); off += (size_t)SEQ * 3 * DIM * 2;       // 12.6 MB
    unsigned short* xb   = (unsigned short*)(ws + off); off += (size_t)SEQ * DIM * 2;           //  4.2 MB
    unsigned short* kvs  = (unsigned short*)(ws + off); off += (size_t)NH * NCK * KVR * 64 * 2; //  4.3 MB
    unsigned short* kvpb = (unsigned short*)(ws + off); off += (size_t)NH * NCK * KVR * 64 * 2; //  4.3 MB
    unsigned short* wqt  = (unsigned short*)(ws + off); off += (size_t)3 * DIM * DIM * 2;       //  6.3 MB
    unsigned short* wot  = (unsigned short*)(ws + off); off += (size_t)DIM * DIM * 2;           //  2.1 MB
    unsigned short* attnb = xb;   // alias: qkv-GEMM finishes reading xb first (stream order)

    dim3 blk(256);

    prep_fused<<<dim3(2048 + 96 * 32 + 32 * 32), blk, 0, stream>>>(
        x, xb, W_qkv, wqt, W_out, wot);

    // qkv = x @ W_qkv (phi fused): BM=128, BN=96, 4 waves (2x2, per-wave 64x48),
    // A 2-slot + B 3-slot = 68KB LDS -> 2 blocks/CU; grid 32x16 = 512 = 2/CU.
    gemm_pipe<2, 2, 3, 2, 3, 2, 1, 1><<<dim3(3 * DIM / 96, SEQ / 128), dim3(256), 0, stream>>>(
        xb, wqt, qkvb, SEQ, 3 * DIM, DIM);

    chunk_kv<<<dim3(NCK, NH), blk, 0, stream>>>(qkvb, kvs);
    scan_kv<<<dim3((NH * KVR * 64 + 255) / 256), blk, 0, stream>>>(kvs, kvpb);
    attn_chunk<<<dim3(NCK, NH), blk, 0, stream>>>(qkvb, kvpb, attnb);

    // out = attn @ W_out : BM=64 (WAVES_M=1, 4 waves 1x4, per-wave 64x16),
    // BN=64, 3-slot/3-slot = 48KB LDS -> grid 16x32 = 512 = 2 blocks/CU.
    gemm_pipe<1, 4, 1, 3, 3, 2, 0, 0><<<dim3(DIM / 64, SEQ / 64), dim3(256), 0, stream>>>(
        attnb, wot, out, SEQ, DIM, DIM);
}